// Round 1
// baseline (563.050 us; speedup 1.0000x reference)
//
#include <hip/hip_runtime.h>

typedef __bf16 bf16x8 __attribute__((ext_vector_type(8)));
typedef float  f32x4  __attribute__((ext_vector_type(4)));

#define B_   32
#define OC   256
#define IC   256
#define HW   3136      // 56*56
#define HP   60        // padded rows (2 extra for n-tail overread)
#define WP   58
#define KTOT 2304      // 9 * 256
#define XPAD_BYTES ((size_t)B_ * HP * WP * IC * 2)   // 57,016,320

#define SWZ(r) (((r) >> 1) & 3)

__device__ __forceinline__ void async16(const void* g, void* l) {
    __builtin_amdgcn_global_load_lds(
        (__attribute__((address_space(1))) void*)g,
        (__attribute__((address_space(3))) void*)l, 16, 0, 0);
}

// ---------------- pass 0: zero the padded border of Xpad ----------------
// border cells per b: rows {0,57,58,59} x 58 cols = 232, plus cols {0,57} x rows 1..56 = 112 -> 344
// threads: 344 pos * 32 (ic/8) = 11008 per b; * 32 b = 352256 = 1376 * 256
__global__ __launch_bounds__(256) void zero_border(__bf16* __restrict__ Xpad) {
    int t   = blockIdx.x * 256 + threadIdx.x;
    int b   = t / 11008;
    int r2  = t - b * 11008;
    int pos = r2 >> 5, iq = r2 & 31;
    int r, c;
    if (pos < 232) { int rr = pos / 58; c = pos - rr * 58; r = (rr == 0) ? 0 : (56 + rr); }
    else           { int p2 = pos - 232; r = 1 + (p2 >> 1); c = (p2 & 1) * 57; }
    uint4 z = make_uint4(0u, 0u, 0u, 0u);
    *(uint4*)(Xpad + ((size_t)b * (HP * WP) + r * WP + c) * IC + iq * 8) = z;
}

// ---------------- pass 1: NCHW fp32 -> padded NHWC bf16 ----------------
// grid (49 s-chunks of 64, 8 ic-chunks of 32, 32 b)
__global__ __launch_bounds__(256) void transpose_pad(
    const float* __restrict__ X, __bf16* __restrict__ Xpad) {
    int sc = blockIdx.x, icc = blockIdx.y, b = blockIdx.z;
    __shared__ float lt[64][33];
    int tid = threadIdx.x;
    {
        int ci = tid >> 4, sq = tid & 15;
        const float* base = X + (size_t)(b * IC + icc * 32) * HW + sc * 64;
        float4 v0 = *(const float4*)(base + (size_t)ci * HW + sq * 4);
        float4 v1 = *(const float4*)(base + (size_t)(ci + 16) * HW + sq * 4);
        lt[sq * 4 + 0][ci] = v0.x; lt[sq * 4 + 1][ci] = v0.y;
        lt[sq * 4 + 2][ci] = v0.z; lt[sq * 4 + 3][ci] = v0.w;
        lt[sq * 4 + 0][ci + 16] = v1.x; lt[sq * 4 + 1][ci + 16] = v1.y;
        lt[sq * 4 + 2][ci + 16] = v1.z; lt[sq * 4 + 3][ci + 16] = v1.w;
    }
    __syncthreads();
    {
        int p = tid >> 2, iq = tid & 3;
        int s = sc * 64 + p;
        int h = s / 56, w = s - h * 56;
        __bf16* dst = Xpad + ((size_t)b * (HP * WP) + (h + 1) * WP + (w + 1)) * IC + icc * 32 + iq * 8;
        bf16x8 v;
        #pragma unroll
        for (int j = 0; j < 8; ++j) v[j] = (__bf16)lt[p][iq * 8 + j];
        *(bf16x8*)dst = v;
    }
}

// ---------------- pass 2: weight synthesis -> Asyn[b][oc][tap*256+ic] bf16 ----------------
// one block per (oc, tap); thread = ic; 32 accumulators (one per b)
__global__ __launch_bounds__(256) void synth(
    const float* __restrict__ se, const float* __restrict__ weight,
    __bf16* __restrict__ Asyn) {
    int oc = blockIdx.x / 9, tap = blockIdx.x - oc * 9;
    __shared__ float se_l[2048];   // [32][64]
    int tid = threadIdx.x;
    #pragma unroll
    for (int i = 0; i < 2; ++i)
        ((float4*)se_l)[tid + i * 256] = ((const float4*)se)[tid + i * 256];
    __syncthreads();
    const float* wrow = weight + ((size_t)(oc * 256 + tid) * 9 + tap) * 64;
    float acc[32];
    #pragma unroll
    for (int b = 0; b < 32; ++b) acc[b] = 0.f;
    #pragma unroll
    for (int n4 = 0; n4 < 16; ++n4) {
        float4 w4 = *(const float4*)(wrow + n4 * 4);
        #pragma unroll
        for (int b = 0; b < 32; ++b) {
            float4 s4 = *(const float4*)(se_l + b * 64 + n4 * 4);
            acc[b] += w4.x * s4.x + w4.y * s4.y + w4.z * s4.z + w4.w * s4.w;
        }
    }
    size_t outb = (size_t)oc * KTOT + tap * 256 + tid;
    #pragma unroll
    for (int b = 0; b < 32; ++b)
        Asyn[(size_t)b * OC * KTOT + outb] = (__bf16)acc[b];
}

// ---------------- pass 3: per-sample implicit GEMM, bf16 MFMA ----------------
// C[b][oc][n] = sum_k Asyn[b][oc][k] * Xpad[b][h+kh][w+kw][ic],  k=(tap,ic)
// 128x128 tile, BK=32, 4 waves of 64x64 (4x4 MFMA 16x16x32)
__global__ __launch_bounds__(256) void conv_mfma(
    const __bf16* __restrict__ Asyn, const __bf16* __restrict__ Xpad,
    const float* __restrict__ bias, float* __restrict__ Out) {
    const int ntile = blockIdx.x, mtile = blockIdx.y, b = blockIdx.z;
    __shared__ __bf16 Al[128 * 32];
    __shared__ __bf16 Bl[128 * 32];
    const int tid = threadIdx.x;
    const int wid = tid >> 6, lane = tid & 63;

    // ---- staging setup: each wave stages rows [wid*32, wid*32+32) of A and B,
    //      two global_load_lds (16 rows x 64B) each. Per-lane gather address;
    //      lane l covers tile-row wid*32 + i*16 + (l>>2), physical granule l&3.
    //      XOR-swizzle: logical granule q = (l&3) ^ SWZ(row).
    const int srow = lane >> 2, p = lane & 3;
    const int rl0 = wid * 32 + srow, rl1 = rl0 + 16;
    const int q0 = p ^ SWZ(rl0), q1 = p ^ SWZ(rl1);
    const __bf16* aptr0 = Asyn + (size_t)(b * OC + mtile * 128 + rl0) * KTOT + q0 * 8;
    const __bf16* aptr1 = Asyn + (size_t)(b * OC + mtile * 128 + rl1) * KTOT + q1 * 8;
    const int nn0 = ntile * 128 + rl0, nn1 = ntile * 128 + rl1;   // may exceed 3135 (reads zeros)
    const int h0 = nn0 / 56, w0 = nn0 - h0 * 56;
    const int h1 = nn1 / 56, w1 = nn1 - h1 * 56;
    const __bf16* xb = Xpad + (size_t)b * (HP * WP) * IC;
    const __bf16* bptr0 = xb + ((h0 * WP) + w0) * IC + q0 * 8;
    const __bf16* bptr1 = xb + ((h1 * WP) + w1) * IC + q1 * 8;
    char* alds0 = (char*)Al + (wid * 32) * 64;
    char* alds1 = alds0 + 1024;
    char* blds0 = (char*)Bl + (wid * 32) * 64;
    char* blds1 = blds0 + 1024;

    // ---- compute setup (frag offsets constant across K-loop) ----
    const int wm = wid & 1, wn = wid >> 1;
    const int fr = lane & 15, fq = lane >> 4;
    int aoff[4], boff[4];
    #pragma unroll
    for (int i = 0; i < 4; ++i) {
        int ra = wm * 64 + i * 16 + fr;
        aoff[i] = ra * 32 + (fq ^ SWZ(ra)) * 8;
        int rb = wn * 64 + i * 16 + fr;
        boff[i] = rb * 32 + (fq ^ SWZ(rb)) * 8;
    }
    f32x4 acc[4][4] = {};

    for (int tap = 0; tap < 9; ++tap) {
        const int kh = tap / 3, kw = tap - kh * 3;
        const int bo = (kh * WP + kw) * IC;
        const int ko = tap * 256;
        for (int icc = 0; icc < 8; ++icc) {
            const int kk = ko + icc * 32;
            async16(aptr0 + kk, alds0);
            async16(aptr1 + kk, alds1);
            async16(bptr0 + bo + icc * 32, blds0);
            async16(bptr1 + bo + icc * 32, blds1);
            __syncthreads();
            bf16x8 af[4], bv[4];
            #pragma unroll
            for (int i = 0; i < 4; ++i) {
                af[i] = *(const bf16x8*)(Al + aoff[i]);
                bv[i] = *(const bf16x8*)(Bl + boff[i]);
            }
            #pragma unroll
            for (int mi = 0; mi < 4; ++mi)
                #pragma unroll
                for (int ni = 0; ni < 4; ++ni)
                    acc[mi][ni] = __builtin_amdgcn_mfma_f32_16x16x32_bf16(
                        af[mi], bv[ni], acc[mi][ni], 0, 0, 0);
            __syncthreads();
        }
    }

    // ---- store: D row = fq*4 + reg, col = fr (m89/m91-verified layout) ----
    #pragma unroll
    for (int mi = 0; mi < 4; ++mi) {
        #pragma unroll
        for (int r = 0; r < 4; ++r) {
            const int row = mtile * 128 + wm * 64 + mi * 16 + fq * 4 + r;
            const float bvv = bias[row];
            float* orow = Out + (size_t)(b * OC + row) * HW;
            #pragma unroll
            for (int ni = 0; ni < 4; ++ni) {
                const int col = ntile * 128 + wn * 64 + ni * 16 + fr;
                if (col < HW) orow[col] = acc[mi][ni][r] + bvv;
            }
        }
    }
}

extern "C" void kernel_launch(void* const* d_in, const int* in_sizes, int n_in,
                              void* d_out, int out_size, void* d_ws, size_t ws_size,
                              hipStream_t stream) {
    const float* X    = (const float*)d_in[0];   // [32,256,56,56]
    const float* se   = (const float*)d_in[1];   // [32,64]
    const float* Wt   = (const float*)d_in[2];   // [589824,64]
    const float* bias = (const float*)d_in[3];   // [256]
    __bf16* Xpad = (__bf16*)d_ws;                           // 57.0 MB
    __bf16* Asyn = (__bf16*)((char*)d_ws + XPAD_BYTES);     // 37.75 MB
    float*  Out  = (float*)d_out;

    zero_border<<<1376, 256, 0, stream>>>(Xpad);
    transpose_pad<<<dim3(49, 8, 32), 256, 0, stream>>>(X, Xpad);
    synth<<<2304, 256, 0, stream>>>(se, Wt, Asyn);
    conv_mfma<<<dim3(25, 2, 32), 256, 0, stream>>>(Asyn, Xpad, bias, Out);
}

// Round 2
// 523.912 us; speedup vs baseline: 1.0747x; 1.0747x over previous
//
#include <hip/hip_runtime.h>

typedef __bf16 bf16x8 __attribute__((ext_vector_type(8)));
typedef float  f32x4  __attribute__((ext_vector_type(4)));

#define B_   32
#define OC   256
#define IC   256
#define HW   3136      // 56*56
#define HP   60        // padded rows (2 extra for n-tail overread)
#define WP   58
#define KTOT 2304      // 9 * 256
#define XPAD_BYTES ((size_t)B_ * HP * WP * IC * 2)   // 57,016,320

#define SWZ(r) (((r) >> 1) & 3)

__device__ __forceinline__ void async16(const void* g, void* l) {
    __builtin_amdgcn_global_load_lds(
        (__attribute__((address_space(1))) void*)g,
        (__attribute__((address_space(3))) void*)l, 16, 0, 0);
}

// ---------------- pass 0: zero the padded border of Xpad ----------------
__global__ __launch_bounds__(256) void zero_border(__bf16* __restrict__ Xpad) {
    int t   = blockIdx.x * 256 + threadIdx.x;
    int b   = t / 11008;
    int r2  = t - b * 11008;
    int pos = r2 >> 5, iq = r2 & 31;
    int r, c;
    if (pos < 232) { int rr = pos / 58; c = pos - rr * 58; r = (rr == 0) ? 0 : (56 + rr); }
    else           { int p2 = pos - 232; r = 1 + (p2 >> 1); c = (p2 & 1) * 57; }
    uint4 z = make_uint4(0u, 0u, 0u, 0u);
    *(uint4*)(Xpad + ((size_t)b * (HP * WP) + r * WP + c) * IC + iq * 8) = z;
}

// ---------------- pass 1: NCHW fp32 -> padded NHWC bf16 ----------------
// block = 64 positions x 64 ic; full-line global reads AND writes.
// grid (49 s-chunks, 4 ic-chunks, 32 b)
__global__ __launch_bounds__(256) void transpose_pad(
    const float* __restrict__ X, __bf16* __restrict__ Xpad) {
    int sc = blockIdx.x, icc = blockIdx.y, b = blockIdx.z;
    __shared__ float lt[64][65];
    int tid = threadIdx.x;
    {
        int ci = tid >> 2, sq = tid & 3;   // ci: ic-in-chunk, sq: 16-float pos chunk
        const float* src = X + (size_t)(b * IC + icc * 64 + ci) * HW + sc * 64 + sq * 16;
        float4 v0 = ((const float4*)src)[0];
        float4 v1 = ((const float4*)src)[1];
        float4 v2 = ((const float4*)src)[2];
        float4 v3 = ((const float4*)src)[3];
        float* dst = &lt[ci][sq * 16];
        ((float4*)dst)[0] = v0; ((float4*)dst)[1] = v1;
        ((float4*)dst)[2] = v2; ((float4*)dst)[3] = v3;
    }
    __syncthreads();
    {
        int p = tid >> 2, iq = tid & 3;    // p: position, iq: 16-ic chunk
        int s = sc * 64 + p;
        int h = s / 56, w = s - h * 56;
        __bf16* dst = Xpad + ((size_t)b * (HP * WP) + (h + 1) * WP + (w + 1)) * IC + icc * 64 + iq * 16;
        bf16x8 v0, v1;
        #pragma unroll
        for (int j = 0; j < 8; ++j) v0[j] = (__bf16)lt[iq * 16 + j][p];
        #pragma unroll
        for (int j = 0; j < 8; ++j) v1[j] = (__bf16)lt[iq * 16 + 8 + j][p];
        *(bf16x8*)dst = v0;
        *(bf16x8*)(dst + 8) = v1;
    }
}

// ---------------- pass 2: weight synthesis -> Asyn[b][oc][tap*256+ic] bf16 ----------------
// weight row (64 fp32) held in VGPRs; se read via wave-uniform (scalar) loads.
// Zero LDS traffic. One block per (oc, tap); thread = ic.
__global__ __launch_bounds__(256) void synth(
    const float* __restrict__ se, const float* __restrict__ weight,
    __bf16* __restrict__ Asyn) {
    int oc = blockIdx.x / 9, tap = blockIdx.x - oc * 9;
    int tid = threadIdx.x;
    const float* wrow = weight + ((size_t)(oc * 256 + tid) * 9 + tap) * 64;
    float4 w[16];
    #pragma unroll
    for (int i = 0; i < 16; ++i) w[i] = ((const float4*)wrow)[i];
    size_t outb = (size_t)oc * KTOT + tap * 256 + tid;
    #pragma unroll
    for (int b = 0; b < 32; ++b) {
        const float4* sb = (const float4*)(se + b * 64);  // uniform -> s_load
        float acc = 0.f;
        #pragma unroll
        for (int i = 0; i < 16; ++i) {
            float4 s4 = sb[i];
            acc += w[i].x * s4.x + w[i].y * s4.y + w[i].z * s4.z + w[i].w * s4.w;
        }
        Asyn[(size_t)b * OC * KTOT + outb] = (__bf16)acc;
    }
}

// ---------------- pass 3: per-sample implicit GEMM, bf16 MFMA ----------------
// XCD-swizzled 1-D grid: block i -> xcd = i&7; each XCD works one sample at a
// time (Xpad[b] 1.74 MB + Asyn[b] 1.18 MB fits the 4 MB per-XCD L2).
__global__ __launch_bounds__(256) void conv_mfma(
    const __bf16* __restrict__ Asyn, const __bf16* __restrict__ Xpad,
    const float* __restrict__ bias, float* __restrict__ Out) {
    const int i = blockIdx.x;
    const int xcd = i & 7, slot = i >> 3;        // slot 0..199
    const int bg = slot / 50, r2 = slot - bg * 50;
    const int b = xcd + 8 * bg;                  // 4 samples per XCD, phased
    const int mtile = r2 & 1, ntile = r2 >> 1;   // 2 x 25

    __shared__ __bf16 Al[128 * 32];
    __shared__ __bf16 Bl[128 * 32];
    const int tid = threadIdx.x;
    const int wid = tid >> 6, lane = tid & 63;

    const int srow = lane >> 2, p = lane & 3;
    const int rl0 = wid * 32 + srow, rl1 = rl0 + 16;
    const int q0 = p ^ SWZ(rl0), q1 = p ^ SWZ(rl1);
    const __bf16* aptr0 = Asyn + (size_t)(b * OC + mtile * 128 + rl0) * KTOT + q0 * 8;
    const __bf16* aptr1 = Asyn + (size_t)(b * OC + mtile * 128 + rl1) * KTOT + q1 * 8;
    const int nn0 = ntile * 128 + rl0, nn1 = ntile * 128 + rl1;
    const int h0 = nn0 / 56, w0 = nn0 - h0 * 56;
    const int h1 = nn1 / 56, w1 = nn1 - h1 * 56;
    const __bf16* xb = Xpad + (size_t)b * (HP * WP) * IC;
    const __bf16* bptr0 = xb + ((h0 * WP) + w0) * IC + q0 * 8;
    const __bf16* bptr1 = xb + ((h1 * WP) + w1) * IC + q1 * 8;
    char* alds0 = (char*)Al + (wid * 32) * 64;
    char* alds1 = alds0 + 1024;
    char* blds0 = (char*)Bl + (wid * 32) * 64;
    char* blds1 = blds0 + 1024;

    const int wm = wid & 1, wn = wid >> 1;
    const int fr = lane & 15, fq = lane >> 4;
    int aoff[4], boff[4];
    #pragma unroll
    for (int i2 = 0; i2 < 4; ++i2) {
        int ra = wm * 64 + i2 * 16 + fr;
        aoff[i2] = ra * 32 + (fq ^ SWZ(ra)) * 8;
        int rb = wn * 64 + i2 * 16 + fr;
        boff[i2] = rb * 32 + (fq ^ SWZ(rb)) * 8;
    }
    f32x4 acc[4][4] = {};

    for (int tap = 0; tap < 9; ++tap) {
        const int kh = tap / 3, kw = tap - kh * 3;
        const int bo = (kh * WP + kw) * IC;
        const int ko = tap * 256;
        for (int icc = 0; icc < 8; ++icc) {
            const int kk = ko + icc * 32;
            async16(aptr0 + kk, alds0);
            async16(aptr1 + kk, alds1);
            async16(bptr0 + bo + icc * 32, blds0);
            async16(bptr1 + bo + icc * 32, blds1);
            __syncthreads();
            bf16x8 af[4], bv[4];
            #pragma unroll
            for (int i2 = 0; i2 < 4; ++i2) {
                af[i2] = *(const bf16x8*)(Al + aoff[i2]);
                bv[i2] = *(const bf16x8*)(Bl + boff[i2]);
            }
            #pragma unroll
            for (int mi = 0; mi < 4; ++mi)
                #pragma unroll
                for (int ni = 0; ni < 4; ++ni)
                    acc[mi][ni] = __builtin_amdgcn_mfma_f32_16x16x32_bf16(
                        af[mi], bv[ni], acc[mi][ni], 0, 0, 0);
            __syncthreads();
        }
    }

    #pragma unroll
    for (int mi = 0; mi < 4; ++mi) {
        #pragma unroll
        for (int r = 0; r < 4; ++r) {
            const int row = mtile * 128 + wm * 64 + mi * 16 + fq * 4 + r;
            const float bvv = bias[row];
            float* orow = Out + (size_t)(b * OC + row) * HW;
            #pragma unroll
            for (int ni = 0; ni < 4; ++ni) {
                const int col = ntile * 128 + wn * 64 + ni * 16 + fr;
                if (col < HW) orow[col] = acc[mi][ni][r] + bvv;
            }
        }
    }
}

extern "C" void kernel_launch(void* const* d_in, const int* in_sizes, int n_in,
                              void* d_out, int out_size, void* d_ws, size_t ws_size,
                              hipStream_t stream) {
    const float* X    = (const float*)d_in[0];   // [32,256,56,56]
    const float* se   = (const float*)d_in[1];   // [32,64]
    const float* Wt   = (const float*)d_in[2];   // [589824,64]
    const float* bias = (const float*)d_in[3];   // [256]
    __bf16* Xpad = (__bf16*)d_ws;                           // 57.0 MB
    __bf16* Asyn = (__bf16*)((char*)d_ws + XPAD_BYTES);     // 37.75 MB
    float*  Out  = (float*)d_out;

    zero_border<<<1376, 256, 0, stream>>>(Xpad);
    transpose_pad<<<dim3(49, 4, 32), 256, 0, stream>>>(X, Xpad);
    synth<<<2304, 256, 0, stream>>>(se, Wt, Asyn);
    conv_mfma<<<1600, 256, 0, stream>>>(Asyn, Xpad, bias, Out);
}

// Round 3
// 512.871 us; speedup vs baseline: 1.0978x; 1.0215x over previous
//
#include <hip/hip_runtime.h>

typedef __bf16 bf16x8 __attribute__((ext_vector_type(8)));
typedef float  f32x4  __attribute__((ext_vector_type(4)));

#define B_   32
#define OC   256
#define IC   256
#define HW   3136      // 56*56
#define HP   60        // padded rows (2 extra for n-tail overread)
#define WP   58
#define KTOT 2304      // 9 * 256
#define XPAD_BYTES ((size_t)B_ * HP * WP * IC * 2)   // 57,016,320

__device__ __forceinline__ void async16(const void* g, void* l) {
    __builtin_amdgcn_global_load_lds(
        (__attribute__((address_space(1))) void*)g,
        (__attribute__((address_space(3))) void*)l, 16, 0, 0);
}

// ---------------- pass 0: zero the padded border of Xpad ----------------
__global__ __launch_bounds__(256) void zero_border(__bf16* __restrict__ Xpad) {
    int t   = blockIdx.x * 256 + threadIdx.x;
    int b   = t / 11008;
    int r2  = t - b * 11008;
    int pos = r2 >> 5, iq = r2 & 31;
    int r, c;
    if (pos < 232) { int rr = pos / 58; c = pos - rr * 58; r = (rr == 0) ? 0 : (56 + rr); }
    else           { int p2 = pos - 232; r = 1 + (p2 >> 1); c = (p2 & 1) * 57; }
    uint4 z = make_uint4(0u, 0u, 0u, 0u);
    *(uint4*)(Xpad + ((size_t)b * (HP * WP) + r * WP + c) * IC + iq * 8) = z;
}

// ---------------- pass 1: NCHW fp32 -> padded NHWC bf16 ----------------
__global__ __launch_bounds__(256) void transpose_pad(
    const float* __restrict__ X, __bf16* __restrict__ Xpad) {
    int sc = blockIdx.x, icc = blockIdx.y, b = blockIdx.z;
    __shared__ float lt[64][65];
    int tid = threadIdx.x;
    {
        int ci = tid >> 2, sq = tid & 3;
        const float* src = X + (size_t)(b * IC + icc * 64 + ci) * HW + sc * 64 + sq * 16;
        float4 v0 = ((const float4*)src)[0];
        float4 v1 = ((const float4*)src)[1];
        float4 v2 = ((const float4*)src)[2];
        float4 v3 = ((const float4*)src)[3];
        float* dst = &lt[ci][sq * 16];
        ((float4*)dst)[0] = v0; ((float4*)dst)[1] = v1;
        ((float4*)dst)[2] = v2; ((float4*)dst)[3] = v3;
    }
    __syncthreads();
    {
        int p = tid >> 2, iq = tid & 3;
        int s = sc * 64 + p;
        int h = s / 56, w = s - h * 56;
        __bf16* dst = Xpad + ((size_t)b * (HP * WP) + (h + 1) * WP + (w + 1)) * IC + icc * 64 + iq * 16;
        bf16x8 v0, v1;
        #pragma unroll
        for (int j = 0; j < 8; ++j) v0[j] = (__bf16)lt[iq * 16 + j][p];
        #pragma unroll
        for (int j = 0; j < 8; ++j) v1[j] = (__bf16)lt[iq * 16 + 8 + j][p];
        *(bf16x8*)dst = v0;
        *(bf16x8*)(dst + 8) = v1;
    }
}

// ---------------- pass 2: weight synthesis -> Asyn[b][oc][tap*256+ic] bf16 ----------------
__global__ __launch_bounds__(256) void synth(
    const float* __restrict__ se, const float* __restrict__ weight,
    __bf16* __restrict__ Asyn) {
    int oc = blockIdx.x / 9, tap = blockIdx.x - oc * 9;
    int tid = threadIdx.x;
    const float* wrow = weight + ((size_t)(oc * 256 + tid) * 9 + tap) * 64;
    float4 w[16];
    #pragma unroll
    for (int i = 0; i < 16; ++i) w[i] = ((const float4*)wrow)[i];
    size_t outb = (size_t)oc * KTOT + tap * 256 + tid;
    #pragma unroll
    for (int b = 0; b < 32; ++b) {
        const float4* sb = (const float4*)(se + b * 64);  // uniform -> s_load
        float acc = 0.f;
        #pragma unroll
        for (int i = 0; i < 16; ++i) {
            float4 s4 = sb[i];
            acc += w[i].x * s4.x + w[i].y * s4.y + w[i].z * s4.z + w[i].w * s4.w;
        }
        Asyn[(size_t)b * OC * KTOT + outb] = (__bf16)acc;
    }
}

// ---------------- pass 3: per-sample implicit GEMM, bf16 MFMA, BK=64 ----------------
// XCD-swizzled 1-D grid; 128x128 tile; 36 barrier-pairs of {32KB stage, 32 MFMA/wave}.
// LDS row = 128 B (64 bf16 k). XOR swizzle: granule g of row r stored at g^(r&7).
__global__ __launch_bounds__(256) void conv_mfma(
    const __bf16* __restrict__ Asyn, const __bf16* __restrict__ Xpad,
    const float* __restrict__ bias, float* __restrict__ Out) {
    const int i = blockIdx.x;
    const int xcd = i & 7, slot = i >> 3;        // slot 0..199
    const int bg = slot / 50, r2 = slot - bg * 50;
    const int b = xcd + 8 * bg;                  // 4 samples per XCD, phased
    const int mtile = r2 & 1, ntile = r2 >> 1;   // 2 x 25

    __shared__ __bf16 Al[128 * 64];
    __shared__ __bf16 Bl[128 * 64];
    const int tid = threadIdx.x;
    const int wid = tid >> 6, lane = tid & 63;

    // ---- staging: wave stages rows [wid*32, wid*32+32) of A and B as 4 chunks
    //      of 8 rows; one async16 covers 8 rows x 128 B. lane -> row lane>>3,
    //      physical granule lane&7, logical granule q = (lane&7)^(lane>>3).
    const int rsub = lane >> 3;
    const int q = (lane & 7) ^ rsub;
    const __bf16* ap[4]; const __bf16* bp[4];
    char* alds[4]; char* blds[4];
    const __bf16* xb = Xpad + (size_t)b * (HP * WP) * IC;
    #pragma unroll
    for (int c = 0; c < 4; ++c) {
        const int r = wid * 32 + c * 8 + rsub;
        ap[c] = Asyn + (size_t)(b * OC + mtile * 128 + r) * KTOT + q * 8;
        const int nn = ntile * 128 + r;          // may exceed 3135 (reads zeros)
        const int h = nn / 56, w = nn - h * 56;
        bp[c] = xb + (h * WP + w) * IC + q * 8;
        alds[c] = (char*)Al + (wid * 32 + c * 8) * 128;
        blds[c] = (char*)Bl + (wid * 32 + c * 8) * 128;
    }

    // ---- fragment read offsets (bytes). Row r granule g at r*128 + (g^(r&7))*16.
    //      k-half t flips granule bit2 -> byte offset ^64.
    const int wm = wid & 1, wn = wid >> 1;
    const int fr = lane & 15, fq = lane >> 4;
    int aoff[4], boff[4];
    #pragma unroll
    for (int i2 = 0; i2 < 4; ++i2) {
        const int ra = wm * 64 + i2 * 16 + fr;
        aoff[i2] = ra * 128 + ((fq ^ (ra & 7)) * 16);
        const int rb = wn * 64 + i2 * 16 + fr;
        boff[i2] = rb * 128 + ((fq ^ (rb & 7)) * 16);
    }
    f32x4 acc[4][4] = {};

    for (int tap = 0; tap < 9; ++tap) {
        const int kh = tap / 3, kw = tap - kh * 3;
        const int boB = (kh * WP + kw) * IC;     // element offset into Xpad
        const int aoA = tap * 256;               // element offset into Asyn row
        #pragma unroll
        for (int sub = 0; sub < 4; ++sub) {
            const int ka = aoA + sub * 64;
            const int kb = boB + sub * 64;
            #pragma unroll
            for (int c = 0; c < 4; ++c) async16(ap[c] + ka, alds[c]);
            #pragma unroll
            for (int c = 0; c < 4; ++c) async16(bp[c] + kb, blds[c]);
            __syncthreads();
            #pragma unroll
            for (int t = 0; t < 2; ++t) {
                bf16x8 af[4], bv[4];
                #pragma unroll
                for (int i2 = 0; i2 < 4; ++i2) {
                    af[i2] = *(const bf16x8*)((char*)Al + (aoff[i2] ^ (t * 64)));
                    bv[i2] = *(const bf16x8*)((char*)Bl + (boff[i2] ^ (t * 64)));
                }
                #pragma unroll
                for (int mi = 0; mi < 4; ++mi)
                    #pragma unroll
                    for (int ni = 0; ni < 4; ++ni)
                        acc[mi][ni] = __builtin_amdgcn_mfma_f32_16x16x32_bf16(
                            af[mi], bv[ni], acc[mi][ni], 0, 0, 0);
            }
            __syncthreads();
        }
    }

    // ---- store: D row = fq*4 + reg, col = fr ----
    #pragma unroll
    for (int mi = 0; mi < 4; ++mi) {
        #pragma unroll
        for (int r = 0; r < 4; ++r) {
            const int row = mtile * 128 + wm * 64 + mi * 16 + fq * 4 + r;
            const float bvv = bias[row];
            float* orow = Out + (size_t)(b * OC + row) * HW;
            #pragma unroll
            for (int ni = 0; ni < 4; ++ni) {
                const int col = ntile * 128 + wn * 64 + ni * 16 + fr;
                if (col < HW) orow[col] = acc[mi][ni][r] + bvv;
            }
        }
    }
}

extern "C" void kernel_launch(void* const* d_in, const int* in_sizes, int n_in,
                              void* d_out, int out_size, void* d_ws, size_t ws_size,
                              hipStream_t stream) {
    const float* X    = (const float*)d_in[0];   // [32,256,56,56]
    const float* se   = (const float*)d_in[1];   // [32,64]
    const float* Wt   = (const float*)d_in[2];   // [589824,64]
    const float* bias = (const float*)d_in[3];   // [256]
    __bf16* Xpad = (__bf16*)d_ws;                           // 57.0 MB
    __bf16* Asyn = (__bf16*)((char*)d_ws + XPAD_BYTES);     // 37.75 MB
    float*  Out  = (float*)d_out;

    zero_border<<<1376, 256, 0, stream>>>(Xpad);
    transpose_pad<<<dim3(49, 4, 32), 256, 0, stream>>>(X, Xpad);
    synth<<<2304, 256, 0, stream>>>(se, Wt, Asyn);
    conv_mfma<<<1600, 256, 0, stream>>>(Asyn, Xpad, bias, Out);
}